// Round 1
// baseline (708.522 us; speedup 1.0000x reference)
//
#include <hip/hip_runtime.h>

#define NB   512
#define NN   50
#define LLn  50
#define HD   128
#define OUTN 99999

// ---------------- ws layout (floats) ----------------
// 0       W_einT  [128][128]
// 16384   W_eoutT [128][128]
// 32768   w_ihT   [256][384]
// 131072  w_hhT   [128][384]
// 180224  W1T     [128][128]
// 196608  W2T     [128][128]
// 212992  WtT     [256][128]
// 245760  a_final [512][128]

__global__ void k0_prep(const float* __restrict__ w_ih, const float* __restrict__ w_hh,
                        const float* __restrict__ W_ein, const float* __restrict__ W_eout,
                        const float* __restrict__ W1, const float* __restrict__ W2,
                        const float* __restrict__ Wt, float* __restrict__ ws)
{
  for (int i = blockIdx.x * blockDim.x + threadIdx.x; i < 245760; i += gridDim.x * blockDim.x) {
    int idx = i;
    if (idx < 16384) { int k = idx >> 7, c = idx & 127; ws[idx] = W_ein[c*128 + k]; continue; }
    idx -= 16384;
    if (idx < 16384) { int k = idx >> 7, c = idx & 127; ws[16384 + idx] = W_eout[c*128 + k]; continue; }
    idx -= 16384;
    if (idx < 98304) { int k = idx / 384, r = idx % 384; ws[32768 + idx] = w_ih[r*256 + k]; continue; }
    idx -= 98304;
    if (idx < 49152) { int k = idx / 384, r = idx % 384; ws[131072 + idx] = w_hh[r*128 + k]; continue; }
    idx -= 49152;
    if (idx < 16384) { int k = idx >> 7, c = idx & 127; ws[180224 + idx] = W1[c*128 + k]; continue; }
    idx -= 16384;
    if (idx < 16384) { int k = idx >> 7, c = idx & 127; ws[196608 + idx] = W2[c*128 + k]; continue; }
    idx -= 16384;
    { int k = idx >> 7, c = idx & 127; ws[212992 + idx] = Wt[c*256 + k]; }
  }
}

// GRU for CNT row-pairs (rows n = 2*(i0+i)+half), accumulators in registers.
template<int CNT>
__device__ __forceinline__ void gru_rows(int i0, int half, int c,
    float* __restrict__ S_hid, const float* __restrict__ S_in, const float* __restrict__ S_out,
    const float* __restrict__ w_ihT, const float* __restrict__ w_hhT,
    float bir, float bii, float bin_, float bhr, float bhi, float bhn)
{
  float gr[CNT], gi_[CNT], gn_[CNT], hr[CNT], hi_[CNT], hn_[CNT];
#pragma unroll
  for (int i = 0; i < CNT; ++i) { gr[i]=bir; gi_[i]=bii; gn_[i]=bin_; hr[i]=bhr; hi_[i]=bhi; hn_[i]=bhn; }
  // gh = hidden @ w_hh.T
  for (int k = 0; k < HD; ++k) {
    const float* w = w_hhT + k*384;
    float wr = w[c], wi = w[128+c], wn = w[256+c];
#pragma unroll
    for (int i = 0; i < CNT; ++i) {
      float x = S_hid[(2*(i0+i)+half)*HD + k];
      hr[i] += x*wr; hi_[i] += x*wi; hn_[i] += x*wn;
    }
  }
  // gi = [h_in, h_out] @ w_ih.T
  for (int k = 0; k < HD; ++k) {
    const float* w = w_ihT + k*384;
    float wr = w[c], wi = w[128+c], wn = w[256+c];
#pragma unroll
    for (int i = 0; i < CNT; ++i) {
      float x = S_in[(2*(i0+i)+half)*HD + k];
      gr[i] += x*wr; gi_[i] += x*wi; gn_[i] += x*wn;
    }
  }
  for (int k = 0; k < HD; ++k) {
    const float* w = w_ihT + (128+k)*384;
    float wr = w[c], wi = w[128+c], wn = w[256+c];
#pragma unroll
    for (int i = 0; i < CNT; ++i) {
      float x = S_out[(2*(i0+i)+half)*HD + k];
      gr[i] += x*wr; gi_[i] += x*wi; gn_[i] += x*wn;
    }
  }
  __syncthreads();  // all gh reads of S_hid done before in-place update
#pragma unroll
  for (int i = 0; i < CNT; ++i) {
    int n = 2*(i0+i)+half;
    float rg = 1.f/(1.f + __expf(-(gr[i] + hr[i])));
    float ig = 1.f/(1.f + __expf(-(gi_[i] + hi_[i])));
    float ng = tanhf(gn_[i] + rg*hn_[i]);
    float h = S_hid[n*HD + c];
    S_hid[n*HD + c] = ng + ig*(h - ng);
  }
}

// Fused per-sample GNN step + attention readout. One block per batch sample.
// Dyn LDS: S_hid 6400 | S_in 6400 | S_out 6400 | q1 128 | a 128 | alpha 64 | alias 64
__global__ __launch_bounds__(256) void k1_fused(
    const int* __restrict__ items, const float* __restrict__ A, const int* __restrict__ alias_in,
    const float* __restrict__ emb,
    const float* __restrict__ b_ih, const float* __restrict__ b_hh,
    const float* __restrict__ b_iah, const float* __restrict__ b_oah,
    const float* __restrict__ b_ein, const float* __restrict__ b_eout,
    const float* __restrict__ b1, const float* __restrict__ b2,
    const float* __restrict__ W3, const float* __restrict__ bt_,
    const float* __restrict__ ws, float* __restrict__ a_final)
{
  const int b   = blockIdx.x;
  const int tid = threadIdx.x;
  const int c = tid & 127, half = tid >> 7;

  extern __shared__ float lds[];
  float* S_hid   = lds;          // 6400
  float* S_in    = lds + 6400;   // 6400
  float* S_out   = lds + 12800;  // 6400
  float* S_q1    = lds + 19200;  // 128
  float* S_a     = lds + 19328;  // 128
  float* S_alpha = lds + 19456;  // 64
  int*   S_alias = (int*)(lds + 19520); // 64

  const float* W_einT  = ws;
  const float* W_eoutT = ws + 16384;
  const float* w_ihT   = ws + 32768;
  const float* w_hhT   = ws + 131072;
  const float* W1T     = ws + 180224;
  const float* W2T     = ws + 196608;
  const float* WtT     = ws + 212992;

  // ---- A: gather hidden = embedding[items] ----
  for (int idx = tid; idx < NN*HD; idx += 256) {
    int n = idx >> 7, k = idx & 127;
    S_hid[idx] = emb[(size_t)items[b*NN + n] * HD + k];
  }
  __syncthreads();

  // ---- B: he_in = hidden@W_ein.T + b_ein ; he_out likewise ----
  {
    float accI[25], accO[25];
    float bei = b_ein[c], beo = b_eout[c];
#pragma unroll
    for (int i = 0; i < 25; ++i) { accI[i] = bei; accO[i] = beo; }
    for (int k = 0; k < HD; ++k) {
      float wi = W_einT[(k<<7) + c];
      float wo = W_eoutT[(k<<7) + c];
#pragma unroll
      for (int i = 0; i < 25; ++i) {
        float x = S_hid[(2*i+half)*HD + k];
        accI[i] += x * wi;
        accO[i] += x * wo;
      }
    }
#pragma unroll
    for (int i = 0; i < 25; ++i) {
      S_in [(2*i+half)*HD + c] = accI[i];
      S_out[(2*i+half)*HD + c] = accO[i];
    }
  }
  __syncthreads();

  // ---- C: h_in = A_in@he_in + b_iah ; h_out = A_out@he_out + b_oah ----
  {
    float hin[25], hout[25];
    float bi = b_iah[c], bo = b_oah[c];
#pragma unroll
    for (int i = 0; i < 25; ++i) { hin[i] = bi; hout[i] = bo; }
    const float* Ab = A + (size_t)b * NN * 100;
    for (int m = 0; m < NN; ++m) {
      float xin  = S_in [m*HD + c];
      float xout = S_out[m*HD + c];
#pragma unroll
      for (int i = 0; i < 25; ++i) {
        int n = 2*i + half;
        hin[i]  += Ab[n*100 + m]      * xin;
        hout[i] += Ab[n*100 + 50 + m] * xout;
      }
    }
    __syncthreads();  // all reads of he_in/he_out done before overwrite
#pragma unroll
    for (int i = 0; i < 25; ++i) {
      S_in [(2*i+half)*HD + c] = hin[i];
      S_out[(2*i+half)*HD + c] = hout[i];
    }
  }
  __syncthreads();

  // ---- D+E: GRU (two row-groups to bound register pressure) ----
  {
    float bir = b_ih[c], bii = b_ih[128+c], bin_ = b_ih[256+c];
    float bhr = b_hh[c], bhi = b_hh[128+c], bhn  = b_hh[256+c];
    gru_rows<13>(0,  half, c, S_hid, S_in, S_out, w_ihT, w_hhT, bir, bii, bin_, bhr, bhi, bhn);
    gru_rows<12>(13, half, c, S_hid, S_in, S_out, w_ihT, w_hhT, bir, bii, bin_, bhr, bhi, bhn);
  }
  __syncthreads();

  // ---- F: attention readout ----
  if (tid < LLn) S_alias[tid] = alias_in[b*LLn + tid];
  __syncthreads();

  int cnt = 0;
  for (int l = 0; l < LLn; ++l) cnt += (S_alias[l] > 0) ? 1 : 0;
  int last = cnt - 1; if (last < 0) last = LLn - 1;
  const int a_last = S_alias[last];

  if (tid < HD) {
    float q = b1[tid];
    for (int k = 0; k < HD; ++k) q += S_hid[a_last*HD + k] * W1T[(k<<7) + tid];
    S_q1[tid] = q;
  }
  __syncthreads();

  // sig(l,c) = sigmoid(q1[c] + q2[l][c]) stored at stride 132 over S_in/S_out region
  {
    int al_[25];
#pragma unroll
    for (int i = 0; i < 25; ++i) al_[i] = S_alias[2*i + half];
    float q2a[25];
    float b2c = b2[c];
#pragma unroll
    for (int i = 0; i < 25; ++i) q2a[i] = b2c;
    for (int k = 0; k < HD; ++k) {
      float w = W2T[(k<<7) + c];
#pragma unroll
      for (int i = 0; i < 25; ++i) q2a[i] += S_hid[al_[i]*HD + k] * w;
    }
    float q1c = S_q1[c];
    __syncthreads();  // everyone done reading S_hid/S_q1 before S_in region reused
#pragma unroll
    for (int i = 0; i < 25; ++i) {
      int l = 2*i + half;
      S_in[l*132 + c] = 1.f/(1.f + __expf(-(q1c + q2a[i])));
    }
  }
  __syncthreads();

  if (tid < LLn) {
    int l = tid;
    float s = 0.f;
    for (int cc = 0; cc < HD; ++cc) s += S_in[l*132 + cc] * W3[cc];
    S_alpha[l] = (S_alias[l] > 0) ? s : 0.f;  // fold mask into alpha
  }
  __syncthreads();

  if (tid < HD) {
    float acc = 0.f;
    for (int l = 0; l < LLn; ++l) acc += S_alpha[l] * S_hid[S_alias[l]*HD + tid];
    S_a[tid] = acc;
  }
  __syncthreads();

  if (tid < HD) {
    float r = bt_[tid];
    for (int k = 0; k < HD; ++k) r += S_a[k]                 * WtT[(k<<7)       + tid];
    for (int k = 0; k < HD; ++k) r += S_hid[a_last*HD + k]   * WtT[((128+k)<<7) + tid];
    a_final[b*HD + tid] = r;
  }
}

// scores = a_final (512x128) @ emb[1:].T (128 x 99999), fp32 vector GEMM.
// Tiles: 128(b) x 128(j), K=128 single pass; thread tile 8x8; padded LDS stride 132.
__global__ __launch_bounds__(256) void k2_scores(const float* __restrict__ a_final,
                                                 const float* __restrict__ emb,
                                                 float* __restrict__ out)
{
  const int j0 = blockIdx.x * 128, b0 = blockIdx.y * 128;
  extern __shared__ float lds[];
  float* Al = lds;              // 128 x 132
  float* El = lds + 128*132;    // 128 x 132
  const int tid = threadIdx.x;

  for (int idx = tid; idx < 128*128; idx += 256) {
    int r = idx >> 7, k = idx & 127;
    Al[r*132 + k] = a_final[(b0 + r)*HD + k];
    int j = j0 + r; if (j > OUTN - 1) j = OUTN - 1;
    El[r*132 + k] = emb[(size_t)(1 + j)*HD + k];
  }
  __syncthreads();

  const int tx = tid & 15, ty = tid >> 4;
  float acc[8][8];
#pragma unroll
  for (int r = 0; r < 8; ++r)
#pragma unroll
    for (int c2 = 0; c2 < 8; ++c2) acc[r][c2] = 0.f;

  for (int k = 0; k < HD; k += 4) {
    float4 a4[8], e4[8];
#pragma unroll
    for (int r = 0; r < 8; ++r)  a4[r]  = *(const float4*)&Al[(ty + 16*r )*132 + k];
#pragma unroll
    for (int c2 = 0; c2 < 8; ++c2) e4[c2] = *(const float4*)&El[(tx + 16*c2)*132 + k];
#pragma unroll
    for (int r = 0; r < 8; ++r)
#pragma unroll
      for (int c2 = 0; c2 < 8; ++c2)
        acc[r][c2] += a4[r].x*e4[c2].x + a4[r].y*e4[c2].y + a4[r].z*e4[c2].z + a4[r].w*e4[c2].w;
  }

#pragma unroll
  for (int r = 0; r < 8; ++r) {
    int b = b0 + ty + 16*r;
#pragma unroll
    for (int c2 = 0; c2 < 8; ++c2) {
      int j = j0 + tx + 16*c2;
      if (j < OUTN) out[(size_t)b*OUTN + j] = acc[r][c2];
    }
  }
}

extern "C" void kernel_launch(void* const* d_in, const int* in_sizes, int n_in,
                              void* d_out, int out_size, void* d_ws, size_t ws_size,
                              hipStream_t stream)
{
  const int*   items  = (const int*)  d_in[0];
  const float* A      = (const float*)d_in[1];
  const int*   alias  = (const int*)  d_in[2];
  const float* emb    = (const float*)d_in[3];
  const float* w_ih   = (const float*)d_in[4];
  const float* w_hh   = (const float*)d_in[5];
  const float* b_ih   = (const float*)d_in[6];
  const float* b_hh   = (const float*)d_in[7];
  const float* b_iah  = (const float*)d_in[8];
  const float* b_oah  = (const float*)d_in[9];
  const float* W_ein  = (const float*)d_in[10];
  const float* b_ein  = (const float*)d_in[11];
  const float* W_eout = (const float*)d_in[12];
  const float* b_eout = (const float*)d_in[13];
  const float* W1     = (const float*)d_in[14];
  const float* b1     = (const float*)d_in[15];
  const float* W2     = (const float*)d_in[16];
  const float* b2     = (const float*)d_in[17];
  const float* W3     = (const float*)d_in[18];
  const float* Wt     = (const float*)d_in[19];
  const float* bt_    = (const float*)d_in[20];

  float* ws      = (float*)d_ws;
  float* out     = (float*)d_out;
  float* a_final = ws + 245760;

  k0_prep<<<240, 256, 0, stream>>>(w_ih, w_hh, W_ein, W_eout, W1, W2, Wt, ws);

  k1_fused<<<NB, 256, 19584 * 4, stream>>>(items, A, alias, emb, b_ih, b_hh, b_iah, b_oah,
                                           b_ein, b_eout, b1, b2, W3, bt_, ws, a_final);

  k2_scores<<<dim3(782, 4), 256, 135168, stream>>>(a_final, emb, out);
}

// Round 2
// 363.988 us; speedup vs baseline: 1.9466x; 1.9466x over previous
//
#include <hip/hip_runtime.h>

#define NB   512
#define NN   50
#define LLn  50
#define HD   128
#define OUTN 99999

// ---------------- ws layout ----------------
// floats:
// 0       W_einT  [128][128]
// 16384   W_eoutT [128][128]
// 32768   w_ihT   [256][384]
// 131072  w_hhT   [128][384]
// 180224  W1T     [128][128]
// 196608  W2T     [128][128]
// 212992  WtT     [256][128]
// bytes (after 245760 floats = 983040 B):
// 983040   a_hi image [2 kh][512 b][128 B]  (bf16, row-swizzled)
// 1114112  a_lo image [2 kh][512 b][128 B]
#define WS_AHI 983040
#define WS_ALO 1114112

typedef __attribute__((ext_vector_type(8))) short bf16x8;
typedef __attribute__((ext_vector_type(4))) float f32x4;

__device__ __forceinline__ unsigned short f2bf(float f) {
  unsigned int u = __float_as_uint(f);
  unsigned int r = (u + 0x7FFFu + ((u >> 16) & 1u)) >> 16;
  return (unsigned short)r;
}
__device__ __forceinline__ float bf2f(unsigned short h) {
  return __uint_as_float(((unsigned int)h) << 16);
}
__device__ __forceinline__ void gl_lds16(const void* g, void* l) {
  __builtin_amdgcn_global_load_lds(
      (const __attribute__((address_space(1))) void*)g,
      (__attribute__((address_space(3))) void*)l, 16, 0, 0);
}

__global__ void k0_prep(const float* __restrict__ w_ih, const float* __restrict__ w_hh,
                        const float* __restrict__ W_ein, const float* __restrict__ W_eout,
                        const float* __restrict__ W1, const float* __restrict__ W2,
                        const float* __restrict__ Wt, float* __restrict__ ws)
{
  for (int i = blockIdx.x * blockDim.x + threadIdx.x; i < 245760; i += gridDim.x * blockDim.x) {
    int idx = i;
    if (idx < 16384) { int k = idx >> 7, c = idx & 127; ws[idx] = W_ein[c*128 + k]; continue; }
    idx -= 16384;
    if (idx < 16384) { int k = idx >> 7, c = idx & 127; ws[16384 + idx] = W_eout[c*128 + k]; continue; }
    idx -= 16384;
    if (idx < 98304) { int k = idx / 384, r = idx % 384; ws[32768 + idx] = w_ih[r*256 + k]; continue; }
    idx -= 98304;
    if (idx < 49152) { int k = idx / 384, r = idx % 384; ws[131072 + idx] = w_hh[r*128 + k]; continue; }
    idx -= 49152;
    if (idx < 16384) { int k = idx >> 7, c = idx & 127; ws[180224 + idx] = W1[c*128 + k]; continue; }
    idx -= 16384;
    if (idx < 16384) { int k = idx >> 7, c = idx & 127; ws[196608 + idx] = W2[c*128 + k]; continue; }
    idx -= 16384;
    { int k = idx >> 7, c = idx & 127; ws[212992 + idx] = Wt[c*256 + k]; }
  }
}

// GRU for CNT row-pairs (rows n = 2*(i0+i)+half), accumulators in registers.
template<int CNT>
__device__ __forceinline__ void gru_rows(int i0, int half, int c,
    float* __restrict__ S_hid, const float* __restrict__ S_in, const float* __restrict__ S_out,
    const float* __restrict__ w_ihT, const float* __restrict__ w_hhT,
    float bir, float bii, float bin_, float bhr, float bhi, float bhn)
{
  float gr[CNT], gi_[CNT], gn_[CNT], hr[CNT], hi_[CNT], hn_[CNT];
#pragma unroll
  for (int i = 0; i < CNT; ++i) { gr[i]=bir; gi_[i]=bii; gn_[i]=bin_; hr[i]=bhr; hi_[i]=bhi; hn_[i]=bhn; }
  // gh = hidden @ w_hh.T  (k unrolled x4, float4 LDS reads)
  for (int k = 0; k < HD; k += 4) {
    const float* w = w_hhT + k*384;
    float r0=w[c],       i0_=w[128+c],     n0=w[256+c];
    float r1=w[384+c],   i1=w[512+c],      n1=w[640+c];
    float r2=w[768+c],   i2=w[896+c],      n2=w[1024+c];
    float r3=w[1152+c],  i3=w[1280+c],     n3=w[1408+c];
#pragma unroll
    for (int i = 0; i < CNT; ++i) {
      float4 x = *(const float4*)&S_hid[(2*(i0+i)+half)*HD + k];
      hr[i]  += x.x*r0;  hr[i]  += x.y*r1;  hr[i]  += x.z*r2;  hr[i]  += x.w*r3;
      hi_[i] += x.x*i0_; hi_[i] += x.y*i1;  hi_[i] += x.z*i2;  hi_[i] += x.w*i3;
      hn_[i] += x.x*n0;  hn_[i] += x.y*n1;  hn_[i] += x.z*n2;  hn_[i] += x.w*n3;
    }
  }
  // gi = [h_in, h_out] @ w_ih.T
  for (int k = 0; k < HD; k += 4) {
    const float* w = w_ihT + k*384;
    float r0=w[c],       i0_=w[128+c],     n0=w[256+c];
    float r1=w[384+c],   i1=w[512+c],      n1=w[640+c];
    float r2=w[768+c],   i2=w[896+c],      n2=w[1024+c];
    float r3=w[1152+c],  i3=w[1280+c],     n3=w[1408+c];
#pragma unroll
    for (int i = 0; i < CNT; ++i) {
      float4 x = *(const float4*)&S_in[(2*(i0+i)+half)*HD + k];
      gr[i]  += x.x*r0;  gr[i]  += x.y*r1;  gr[i]  += x.z*r2;  gr[i]  += x.w*r3;
      gi_[i] += x.x*i0_; gi_[i] += x.y*i1;  gi_[i] += x.z*i2;  gi_[i] += x.w*i3;
      gn_[i] += x.x*n0;  gn_[i] += x.y*n1;  gn_[i] += x.z*n2;  gn_[i] += x.w*n3;
    }
  }
  for (int k = 0; k < HD; k += 4) {
    const float* w = w_ihT + (128+k)*384;
    float r0=w[c],       i0_=w[128+c],     n0=w[256+c];
    float r1=w[384+c],   i1=w[512+c],      n1=w[640+c];
    float r2=w[768+c],   i2=w[896+c],      n2=w[1024+c];
    float r3=w[1152+c],  i3=w[1280+c],     n3=w[1408+c];
#pragma unroll
    for (int i = 0; i < CNT; ++i) {
      float4 x = *(const float4*)&S_out[(2*(i0+i)+half)*HD + k];
      gr[i]  += x.x*r0;  gr[i]  += x.y*r1;  gr[i]  += x.z*r2;  gr[i]  += x.w*r3;
      gi_[i] += x.x*i0_; gi_[i] += x.y*i1;  gi_[i] += x.z*i2;  gi_[i] += x.w*i3;
      gn_[i] += x.x*n0;  gn_[i] += x.y*n1;  gn_[i] += x.z*n2;  gn_[i] += x.w*n3;
    }
  }
  __syncthreads();  // all gh reads of S_hid done before in-place update
#pragma unroll
  for (int i = 0; i < CNT; ++i) {
    int n = 2*(i0+i)+half;
    float rg = 1.f/(1.f + __expf(-(gr[i] + hr[i])));
    float ig = 1.f/(1.f + __expf(-(gi_[i] + hi_[i])));
    float ng = tanhf(gn_[i] + rg*hn_[i]);
    float h = S_hid[n*HD + c];
    S_hid[n*HD + c] = ng + ig*(h - ng);
  }
}

// Fused per-sample GNN step + attention readout. One block per batch sample.
__global__ __launch_bounds__(256) void k1_fused(
    const int* __restrict__ items, const float* __restrict__ A, const int* __restrict__ alias_in,
    const float* __restrict__ emb,
    const float* __restrict__ b_ih, const float* __restrict__ b_hh,
    const float* __restrict__ b_iah, const float* __restrict__ b_oah,
    const float* __restrict__ b_ein, const float* __restrict__ b_eout,
    const float* __restrict__ b1, const float* __restrict__ b2,
    const float* __restrict__ W3, const float* __restrict__ bt_,
    float* __restrict__ ws)
{
  const int b   = blockIdx.x;
  const int tid = threadIdx.x;
  const int c = tid & 127, half = tid >> 7;

  extern __shared__ float lds[];
  float* S_hid   = lds;          // 6400
  float* S_in    = lds + 6400;   // 6400
  float* S_out   = lds + 12800;  // 6400
  float* S_q1    = lds + 19200;  // 128
  float* S_a     = lds + 19328;  // 128
  float* S_alpha = lds + 19456;  // 64
  int*   S_alias = (int*)(lds + 19520); // 64

  const float* W_einT  = ws;
  const float* W_eoutT = ws + 16384;
  const float* w_ihT   = ws + 32768;
  const float* w_hhT   = ws + 131072;
  const float* W1T     = ws + 180224;
  const float* W2T     = ws + 196608;
  const float* WtT     = ws + 212992;

  // ---- A: gather hidden = embedding[items] ----
  for (int idx = tid; idx < NN*HD; idx += 256) {
    int n = idx >> 7, k = idx & 127;
    S_hid[idx] = emb[(size_t)items[b*NN + n] * HD + k];
  }
  __syncthreads();

  // ---- B: he_in = hidden@W_ein.T + b_ein ; he_out likewise ----
  {
    float accI[25], accO[25];
    float bei = b_ein[c], beo = b_eout[c];
#pragma unroll
    for (int i = 0; i < 25; ++i) { accI[i] = bei; accO[i] = beo; }
    for (int k = 0; k < HD; k += 4) {
      float wiA = W_einT[(k<<7)+c],     wiB = W_einT[((k+1)<<7)+c];
      float wiC = W_einT[((k+2)<<7)+c], wiD = W_einT[((k+3)<<7)+c];
      float woA = W_eoutT[(k<<7)+c],     woB = W_eoutT[((k+1)<<7)+c];
      float woC = W_eoutT[((k+2)<<7)+c], woD = W_eoutT[((k+3)<<7)+c];
#pragma unroll
      for (int i = 0; i < 25; ++i) {
        float4 x = *(const float4*)&S_hid[(2*i+half)*HD + k];
        accI[i] += x.x*wiA; accI[i] += x.y*wiB; accI[i] += x.z*wiC; accI[i] += x.w*wiD;
        accO[i] += x.x*woA; accO[i] += x.y*woB; accO[i] += x.z*woC; accO[i] += x.w*woD;
      }
    }
#pragma unroll
    for (int i = 0; i < 25; ++i) {
      S_in [(2*i+half)*HD + c] = accI[i];
      S_out[(2*i+half)*HD + c] = accO[i];
    }
  }
  __syncthreads();

  // ---- C: h_in = A_in@he_in + b_iah ; h_out = A_out@he_out + b_oah ----
  {
    float hin[25], hout[25];
    float bi = b_iah[c], bo = b_oah[c];
#pragma unroll
    for (int i = 0; i < 25; ++i) { hin[i] = bi; hout[i] = bo; }
    const float* Ab = A + (size_t)b * NN * 100;
    for (int m = 0; m < NN; ++m) {
      float xin  = S_in [m*HD + c];
      float xout = S_out[m*HD + c];
#pragma unroll
      for (int i = 0; i < 25; ++i) {
        int n = 2*i + half;
        hin[i]  += Ab[n*100 + m]      * xin;
        hout[i] += Ab[n*100 + 50 + m] * xout;
      }
    }
    __syncthreads();  // all reads of he_in/he_out done before overwrite
#pragma unroll
    for (int i = 0; i < 25; ++i) {
      S_in [(2*i+half)*HD + c] = hin[i];
      S_out[(2*i+half)*HD + c] = hout[i];
    }
  }
  __syncthreads();

  // ---- D+E: GRU ----
  {
    float bir = b_ih[c], bii = b_ih[128+c], bin_ = b_ih[256+c];
    float bhr = b_hh[c], bhi = b_hh[128+c], bhn  = b_hh[256+c];
    gru_rows<13>(0,  half, c, S_hid, S_in, S_out, w_ihT, w_hhT, bir, bii, bin_, bhr, bhi, bhn);
    gru_rows<12>(13, half, c, S_hid, S_in, S_out, w_ihT, w_hhT, bir, bii, bin_, bhr, bhi, bhn);
  }
  __syncthreads();

  // ---- F: attention readout ----
  if (tid < LLn) S_alias[tid] = alias_in[b*LLn + tid];
  __syncthreads();

  int cnt = 0;
  for (int l = 0; l < LLn; ++l) cnt += (S_alias[l] > 0) ? 1 : 0;
  int last = cnt - 1; if (last < 0) last = LLn - 1;
  const int a_last = S_alias[last];

  if (tid < HD) {
    float q = b1[tid];
    for (int k = 0; k < HD; ++k) q += S_hid[a_last*HD + k] * W1T[(k<<7) + tid];
    S_q1[tid] = q;
  }
  __syncthreads();

  {
    int al_[25];
#pragma unroll
    for (int i = 0; i < 25; ++i) al_[i] = S_alias[2*i + half];
    float q2a[25];
    float b2c = b2[c];
#pragma unroll
    for (int i = 0; i < 25; ++i) q2a[i] = b2c;
    for (int k = 0; k < HD; k += 4) {
      float w0 = W2T[(k<<7)+c],     w1 = W2T[((k+1)<<7)+c];
      float w2 = W2T[((k+2)<<7)+c], w3 = W2T[((k+3)<<7)+c];
#pragma unroll
      for (int i = 0; i < 25; ++i) {
        float4 x = *(const float4*)&S_hid[al_[i]*HD + k];
        q2a[i] += x.x*w0; q2a[i] += x.y*w1; q2a[i] += x.z*w2; q2a[i] += x.w*w3;
      }
    }
    float q1c = S_q1[c];
    __syncthreads();  // everyone done reading S_hid/S_q1 before S_in region reused
#pragma unroll
    for (int i = 0; i < 25; ++i) {
      int l = 2*i + half;
      S_in[l*132 + c] = 1.f/(1.f + __expf(-(q1c + q2a[i])));
    }
  }
  __syncthreads();

  if (tid < LLn) {
    int l = tid;
    float s = 0.f;
    for (int cc = 0; cc < HD; ++cc) s += S_in[l*132 + cc] * W3[cc];
    S_alpha[l] = (S_alias[l] > 0) ? s : 0.f;
  }
  __syncthreads();

  if (tid < HD) {
    float acc = 0.f;
    for (int l = 0; l < LLn; ++l) acc += S_alpha[l] * S_hid[S_alias[l]*HD + tid];
    S_a[tid] = acc;
  }
  __syncthreads();

  // ---- G: a = concat(a_vec, ht)@Wt.T + bt -> split to bf16 hi/lo swizzled images
  if (tid < HD) {
    float r = bt_[tid];
    for (int k = 0; k < HD; ++k) r += S_a[k]               * WtT[(k<<7)       + tid];
    for (int k = 0; k < HD; ++k) r += S_hid[a_last*HD + k] * WtT[((128+k)<<7) + tid];
    int k = tid, kh = k >> 6, kl = k & 63;
    unsigned int cb = (unsigned int)(kl*2) ^ (((unsigned int)(b & 7)) << 4);
    char* base = (char*)ws;
    unsigned short hi = f2bf(r);
    unsigned short lo = f2bf(r - bf2f(hi));
    *(unsigned short*)(base + WS_AHI + kh*65536 + b*128 + cb) = hi;
    *(unsigned short*)(base + WS_ALO + kh*65536 + b*128 + cb) = lo;
  }
}

// scores = a (512x128) @ emb[1:].T via 3-pass split-bf16 MFMA.
// Block tile 256(b) x 128(j), K staged in 2 halves of 64. 512 threads = 8 waves (4x2).
// LDS: A_hi 32K | A_lo 32K | E_hi 16K | E_lo 16K = 96 KB. XOR row-swizzle on all tiles.
__global__ __launch_bounds__(512) void k2_mfma(const float* __restrict__ emb,
                                               const char* __restrict__ wsb,
                                               float* __restrict__ out)
{
  extern __shared__ char ldsc[];
  char* AHI = ldsc;
  char* ALO = ldsc + 32768;
  char* EHI = ldsc + 65536;
  char* ELO = ldsc + 81920;

  const int tid  = threadIdx.x;
  const int lane = tid & 63;
  const int wid  = tid >> 6;
  const int wm   = wid >> 1;          // 0..3  (64-row band)
  const int wn   = wid & 1;           // 0..1  (64-col band)
  const int j0   = blockIdx.x * 128;
  const int b0   = blockIdx.y * 256;
  const int l15  = lane & 15, l4 = lane >> 4;

  f32x4 acc[4][4];
#pragma unroll
  for (int i = 0; i < 4; ++i)
#pragma unroll
    for (int j = 0; j < 4; ++j) acc[i][j] = (f32x4){0.f, 0.f, 0.f, 0.f};

  for (int kh = 0; kh < 2; ++kh) {
    // A tiles: async global->LDS (linear dest; source image is pre-swizzled)
    const char* srcH = wsb + WS_AHI + kh*65536 + b0*128;
    const char* srcL = wsb + WS_ALO + kh*65536 + b0*128;
#pragma unroll
    for (int r = 0; r < 4; ++r) {
      int off = (r*512 + tid) * 16;
      gl_lds16(srcH + off, AHI + off);
      gl_lds16(srcL + off, ALO + off);
    }
    // E tile: reg-stage fp32 -> hi/lo bf16, swizzled ds_write
    {
      int rbase = tid >> 4, c4 = tid & 15;
#pragma unroll
      for (int rr = 0; rr < 4; ++rr) {
        int row = rbase + rr*32;
        int j = j0 + row; if (j > OUTN - 1) j = OUTN - 1;
        float4 v = *(const float4*)&emb[(size_t)(1 + j)*HD + kh*64 + c4*4];
        unsigned short h0 = f2bf(v.x), h1 = f2bf(v.y), h2 = f2bf(v.z), h3 = f2bf(v.w);
        unsigned short g0 = f2bf(v.x - bf2f(h0)), g1 = f2bf(v.y - bf2f(h1));
        unsigned short g2 = f2bf(v.z - bf2f(h2)), g3 = f2bf(v.w - bf2f(h3));
        unsigned int off = (unsigned int)(row*128) + (((unsigned int)(c4*8)) ^ (((unsigned int)(row&7)) << 4));
        *(ushort4*)(EHI + off) = make_ushort4(h0, h1, h2, h3);
        *(ushort4*)(ELO + off) = make_ushort4(g0, g1, g2, g3);
      }
    }
    __syncthreads();

#pragma unroll
    for (int s = 0; s < 2; ++s) {
      bf16x8 ah[4], al[4], bh[4], bl[4];
      const unsigned int cb = (unsigned int)(s*64 + (l4 << 4));
#pragma unroll
      for (int i = 0; i < 4; ++i) {
        int row = wm*64 + i*16 + l15;
        unsigned int off = (unsigned int)(row*128) + (cb ^ (((unsigned int)(row&7)) << 4));
        ah[i] = *(const bf16x8*)(AHI + off);
        al[i] = *(const bf16x8*)(ALO + off);
      }
#pragma unroll
      for (int j = 0; j < 4; ++j) {
        int row = wn*64 + j*16 + l15;
        unsigned int off = (unsigned int)(row*128) + (cb ^ (((unsigned int)(row&7)) << 4));
        bh[j] = *(const bf16x8*)(EHI + off);
        bl[j] = *(const bf16x8*)(ELO + off);
      }
#pragma unroll
      for (int i = 0; i < 4; ++i)
#pragma unroll
        for (int j = 0; j < 4; ++j) {
          acc[i][j] = __builtin_amdgcn_mfma_f32_16x16x32_bf16(ah[i], bh[j], acc[i][j], 0, 0, 0);
          acc[i][j] = __builtin_amdgcn_mfma_f32_16x16x32_bf16(ah[i], bl[j], acc[i][j], 0, 0, 0);
          acc[i][j] = __builtin_amdgcn_mfma_f32_16x16x32_bf16(al[i], bh[j], acc[i][j], 0, 0, 0);
        }
    }
    __syncthreads();
  }

  // epilogue: D layout col=lane&15, row=(lane>>4)*4+q  [m89]
#pragma unroll
  for (int i = 0; i < 4; ++i) {
#pragma unroll
    for (int j = 0; j < 4; ++j) {
      int jj = j0 + wn*64 + j*16 + l15;
      if (jj < OUTN) {
        size_t rowbase = (size_t)(b0 + wm*64 + i*16 + l4*4);
#pragma unroll
        for (int q = 0; q < 4; ++q)
          out[(rowbase + q)*OUTN + jj] = acc[i][j][q];
      }
    }
  }
}

extern "C" void kernel_launch(void* const* d_in, const int* in_sizes, int n_in,
                              void* d_out, int out_size, void* d_ws, size_t ws_size,
                              hipStream_t stream)
{
  const int*   items  = (const int*)  d_in[0];
  const float* A      = (const float*)d_in[1];
  const int*   alias  = (const int*)  d_in[2];
  const float* emb    = (const float*)d_in[3];
  const float* w_ih   = (const float*)d_in[4];
  const float* w_hh   = (const float*)d_in[5];
  const float* b_ih   = (const float*)d_in[6];
  const float* b_hh   = (const float*)d_in[7];
  const float* b_iah  = (const float*)d_in[8];
  const float* b_oah  = (const float*)d_in[9];
  const float* W_ein  = (const float*)d_in[10];
  const float* b_ein  = (const float*)d_in[11];
  const float* W_eout = (const float*)d_in[12];
  const float* b_eout = (const float*)d_in[13];
  const float* W1     = (const float*)d_in[14];
  const float* b1     = (const float*)d_in[15];
  const float* W2     = (const float*)d_in[16];
  const float* b2     = (const float*)d_in[17];
  const float* W3     = (const float*)d_in[18];
  const float* Wt     = (const float*)d_in[19];
  const float* bt_    = (const float*)d_in[20];

  float* ws  = (float*)d_ws;
  float* out = (float*)d_out;

  k0_prep<<<240, 256, 0, stream>>>(w_ih, w_hh, W_ein, W_eout, W1, W2, Wt, ws);

  k1_fused<<<NB, 256, 19584 * 4, stream>>>(items, A, alias, emb, b_ih, b_hh, b_iah, b_oah,
                                           b_ein, b_eout, b1, b2, W3, bt_, ws);

  k2_mfma<<<dim3(782, 2), 512, 98304, stream>>>(emb, (const char*)d_ws, out);
}

// Round 3
// 257.892 us; speedup vs baseline: 2.7474x; 1.4114x over previous
//
#include <hip/hip_runtime.h>

#define NB   512
#define NN   50
#define LLn  50
#define HD   128
#define OUTN 99999
#define RTOT 25600

// ---------------- ws byte offsets ----------------
#define WS_W1T   0         // fp32 [128][128] transposed
#define WS_W2T   65536     // fp32 [128][128] transposed
#define WS_WTT   131072    // fp32 [256][128] transposed
#define WS_WEH   262144    // bf16 hi [256][128]  (rows 0-127 W_ein, 128-255 W_eout)
#define WS_WEL   327680    // bf16 lo
#define WS_WIHH  393216    // bf16 hi [384][256]
#define WS_WIHL  589824
#define WS_WHHH  786432    // bf16 hi [384][128]
#define WS_WHHL  884736
#define WS_AHI   983040    // a-final hi image [2][512][128B]
#define WS_ALO   1114112

// ---------------- d_out scratch offsets (floats) ----------------
#define SC_H    0          // hidden fp32 [25600][128]
#define SC_HE   3276800    // he fp32 [25600][256]
#define SC_IN   9830400    // inputs fp32 [25600][256]
#define SC_GI   16384000   // gi fp32 [25600][384]
#define SC_H2   26214400   // new hidden fp32 [25600][128]

typedef __attribute__((ext_vector_type(8))) short bf16x8;
typedef __attribute__((ext_vector_type(4))) float f32x4;

__device__ __forceinline__ unsigned short f2bf(float f) {
  unsigned int u = __float_as_uint(f);
  unsigned int r = (u + 0x7FFFu + ((u >> 16) & 1u)) >> 16;
  return (unsigned short)r;
}
__device__ __forceinline__ float bf2f(unsigned short h) {
  return __uint_as_float(((unsigned int)h) << 16);
}
__device__ __forceinline__ void cvt4(float4 v, ushort4& hi, ushort4& lo) {
  unsigned short h0 = f2bf(v.x), h1 = f2bf(v.y), h2 = f2bf(v.z), h3 = f2bf(v.w);
  hi = make_ushort4(h0, h1, h2, h3);
  lo = make_ushort4(f2bf(v.x - bf2f(h0)), f2bf(v.y - bf2f(h1)),
                    f2bf(v.z - bf2f(h2)), f2bf(v.w - bf2f(h3)));
}
__device__ __forceinline__ void gl_lds16(const void* g, void* l) {
  __builtin_amdgcn_global_load_lds(
      (const __attribute__((address_space(1))) void*)g,
      (__attribute__((address_space(3))) void*)l, 16, 0, 0);
}

// ================= k0: weight prep =================
__global__ void k0_prep(const float* __restrict__ w_ih, const float* __restrict__ w_hh,
                        const float* __restrict__ W_ein, const float* __restrict__ W_eout,
                        const float* __restrict__ W1, const float* __restrict__ W2,
                        const float* __restrict__ Wt, char* __restrict__ wsb)
{
  float* wsf = (float*)wsb;
  for (int i = blockIdx.x * blockDim.x + threadIdx.x; i < 245760; i += gridDim.x * blockDim.x) {
    int idx = i;
    if (idx < 16384) { int k = idx >> 7, c = idx & 127; wsf[idx] = W1[c*128 + k]; continue; }
    idx -= 16384;
    if (idx < 16384) { int k = idx >> 7, c = idx & 127; wsf[16384 + idx] = W2[c*128 + k]; continue; }
    idx -= 16384;
    if (idx < 32768) { int k = idx >> 7, c = idx & 127; wsf[32768 + idx] = Wt[c*256 + k]; continue; }
    idx -= 32768;
    if (idx < 32768) {
      int n = idx >> 7, k = idx & 127;
      float v = (n < 128) ? W_ein[n*128 + k] : W_eout[(n-128)*128 + k];
      unsigned short h = f2bf(v);
      *(unsigned short*)(wsb + WS_WEH + idx*2) = h;
      *(unsigned short*)(wsb + WS_WEL + idx*2) = f2bf(v - bf2f(h));
      continue;
    }
    idx -= 32768;
    if (idx < 98304) {
      float v = w_ih[idx];
      unsigned short h = f2bf(v);
      *(unsigned short*)(wsb + WS_WIHH + idx*2) = h;
      *(unsigned short*)(wsb + WS_WIHL + idx*2) = f2bf(v - bf2f(h));
      continue;
    }
    idx -= 98304;
    {
      float v = w_hh[idx];
      unsigned short h = f2bf(v);
      *(unsigned short*)(wsb + WS_WHHH + idx*2) = h;
      *(unsigned short*)(wsb + WS_WHHL + idx*2) = f2bf(v - bf2f(h));
    }
  }
}

// ================= k1a: gather + he GEMM (M=128/blk, N=256, K=128) =================
__global__ __launch_bounds__(512) void k1a_he(const int* __restrict__ items,
    const float* __restrict__ emb, const float* __restrict__ b_ein,
    const float* __restrict__ b_eout, const char* __restrict__ wsb,
    float* __restrict__ outf)
{
  extern __shared__ char lds[];
  char* AH = lds;
  char* AL = lds + 32768;
  float* H  = outf + SC_H;
  float* HE = outf + SC_HE;
  const int tid = threadIdx.x, lane = tid & 63, wid = tid >> 6;
  const int wm = wid >> 2, wn = wid & 3, l15 = lane & 15, l4 = lane >> 4;
  const int r0 = blockIdx.x * 128;

  for (int i = tid; i < 128*32; i += 512) {
    int row = i >> 5, part = i & 31;
    int it = items[r0 + row];
    float4 v = *(const float4*)&emb[(size_t)it*128 + part*4];
    *(float4*)&H[(size_t)(r0+row)*128 + part*4] = v;
    ushort4 hi4, lo4;
    cvt4(v, hi4, lo4);
    unsigned off = row*256 + (((unsigned)(part*8)) ^ (((unsigned)(row&7)) << 4));
    *(ushort4*)(AH + off) = hi4;
    *(ushort4*)(AL + off) = lo4;
  }
  __syncthreads();

  f32x4 acc[4][4];
#pragma unroll
  for (int i = 0; i < 4; ++i)
#pragma unroll
    for (int j = 0; j < 4; ++j) acc[i][j] = (f32x4){0.f,0.f,0.f,0.f};

  for (int s = 0; s < 4; ++s) {
    bf16x8 ah[4], al[4];
#pragma unroll
    for (int i = 0; i < 4; ++i) {
      int row = wm*64 + i*16 + l15;
      unsigned off = row*256 + (((unsigned)(s*64 + l4*16)) ^ (((unsigned)(row&7)) << 4));
      ah[i] = *(const bf16x8*)(AH + off);
      al[i] = *(const bf16x8*)(AL + off);
    }
#pragma unroll
    for (int j = 0; j < 4; ++j) {
      int n = wn*64 + j*16 + l15;
      unsigned boff = (unsigned)(n*256 + s*64 + l4*16);
      bf16x8 bh = *(const bf16x8*)(wsb + WS_WEH + boff);
      bf16x8 bl = *(const bf16x8*)(wsb + WS_WEL + boff);
#pragma unroll
      for (int i = 0; i < 4; ++i) {
        acc[i][j] = __builtin_amdgcn_mfma_f32_16x16x32_bf16(ah[i], bh, acc[i][j], 0,0,0);
        acc[i][j] = __builtin_amdgcn_mfma_f32_16x16x32_bf16(ah[i], bl, acc[i][j], 0,0,0);
        acc[i][j] = __builtin_amdgcn_mfma_f32_16x16x32_bf16(al[i], bh, acc[i][j], 0,0,0);
      }
    }
  }

#pragma unroll
  for (int j = 0; j < 4; ++j) {
    int n = wn*64 + j*16 + l15;
    float bias = (n < 128) ? b_ein[n] : b_eout[n - 128];
#pragma unroll
    for (int i = 0; i < 4; ++i) {
      int rb = r0 + wm*64 + i*16 + l4*4;
#pragma unroll
      for (int q = 0; q < 4; ++q)
        HE[(size_t)(rb + q)*256 + n] = acc[i][j][q] + bias;
    }
  }
}

// ================= k1b: per-sample A @ he (VALU fp32) =================
__global__ __launch_bounds__(256) void k1b_ain(const float* __restrict__ A,
    const float* __restrict__ b_iah, const float* __restrict__ b_oah,
    float* __restrict__ outf)
{
  extern __shared__ float s[];
  float* he_l = s;           // 50*256 = 12800
  float* A_l  = s + 12800;   // [2][50][52] = 5408
  const int b = blockIdx.x, tid = threadIdx.x;
  const float* HE = outf + SC_HE;
  float* IN = outf + SC_IN;

  const float4* he4 = (const float4*)(HE + (size_t)b*NN*256);
  for (int i = tid; i < 3200; i += 256) ((float4*)he_l)[i] = he4[i];
  const float* Ab = A + (size_t)b*NN*100;
  for (int i = tid; i < 5000; i += 256) {
    int n = i / 100, cc = i % 100;
    int sel = (cc >= 50) ? 1 : 0, m = cc - sel*50;
    A_l[sel*2704 + n*52 + m] = Ab[i];
  }
  __syncthreads();

  const int c = tid & 127, sel = tid >> 7;
  const float* Asel = A_l + sel*2704;
  const float* hes  = he_l + sel*128 + c;
  float acc[NN];
#pragma unroll
  for (int n = 0; n < NN; ++n) acc[n] = 0.f;

  for (int m4 = 0; m4 < 48; m4 += 4) {
    float x0 = hes[(m4+0)*256], x1 = hes[(m4+1)*256];
    float x2 = hes[(m4+2)*256], x3 = hes[(m4+3)*256];
#pragma unroll
    for (int n = 0; n < NN; ++n) {
      float4 a = *(const float4*)&Asel[n*52 + m4];
      acc[n] += a.x*x0 + a.y*x1 + a.z*x2 + a.w*x3;
    }
  }
  {
    float x0 = hes[48*256], x1 = hes[49*256];
#pragma unroll
    for (int n = 0; n < NN; ++n)
      acc[n] += Asel[n*52 + 48]*x0 + Asel[n*52 + 49]*x1;
  }
  float bias = sel ? b_oah[c] : b_iah[c];
  for (int n = 0; n < NN; ++n)
    IN[((size_t)b*NN + n)*256 + sel*128 + c] = acc[n] + bias;
}

// ================= k1c: gi = IN @ w_ih.T (M=128/blk, N=384, K=256) =================
__global__ __launch_bounds__(512) void k1c_gi(const char* __restrict__ wsb,
                                              float* __restrict__ outf)
{
  extern __shared__ char lds[];
  char* AH = lds;
  char* AL = lds + 32768;
  const float* IN = outf + SC_IN;
  float* GI = outf + SC_GI;
  const int tid = threadIdx.x, lane = tid & 63, wid = tid >> 6;
  const int wm = wid >> 2, wn = wid & 3, l15 = lane & 15, l4 = lane >> 4;
  const int r0 = blockIdx.x * 128;

  f32x4 acc[4][6];
#pragma unroll
  for (int i = 0; i < 4; ++i)
#pragma unroll
    for (int j = 0; j < 6; ++j) acc[i][j] = (f32x4){0.f,0.f,0.f,0.f};

  for (int kh = 0; kh < 2; ++kh) {
    if (kh) __syncthreads();
    for (int i = tid; i < 128*32; i += 512) {
      int row = i >> 5, part = i & 31;
      float4 v = *(const float4*)&IN[(size_t)(r0+row)*256 + kh*128 + part*4];
      ushort4 hi4, lo4;
      cvt4(v, hi4, lo4);
      unsigned off = row*256 + (((unsigned)(part*8)) ^ (((unsigned)(row&7)) << 4));
      *(ushort4*)(AH + off) = hi4;
      *(ushort4*)(AL + off) = lo4;
    }
    __syncthreads();

    for (int s = 0; s < 4; ++s) {
      bf16x8 ah[4], al[4];
#pragma unroll
      for (int i = 0; i < 4; ++i) {
        int row = wm*64 + i*16 + l15;
        unsigned off = row*256 + (((unsigned)(s*64 + l4*16)) ^ (((unsigned)(row&7)) << 4));
        ah[i] = *(const bf16x8*)(AH + off);
        al[i] = *(const bf16x8*)(AL + off);
      }
#pragma unroll
      for (int j = 0; j < 6; ++j) {
        int n = wn*96 + j*16 + l15;
        unsigned boff = (unsigned)(n*512 + kh*256 + s*64 + l4*16);
        bf16x8 bh = *(const bf16x8*)(wsb + WS_WIHH + boff);
        bf16x8 bl = *(const bf16x8*)(wsb + WS_WIHL + boff);
#pragma unroll
        for (int i = 0; i < 4; ++i) {
          acc[i][j] = __builtin_amdgcn_mfma_f32_16x16x32_bf16(ah[i], bh, acc[i][j], 0,0,0);
          acc[i][j] = __builtin_amdgcn_mfma_f32_16x16x32_bf16(ah[i], bl, acc[i][j], 0,0,0);
          acc[i][j] = __builtin_amdgcn_mfma_f32_16x16x32_bf16(al[i], bh, acc[i][j], 0,0,0);
        }
      }
    }
  }

#pragma unroll
  for (int j = 0; j < 6; ++j) {
    int n = wn*96 + j*16 + l15;
#pragma unroll
    for (int i = 0; i < 4; ++i) {
      int rb = r0 + wm*64 + i*16 + l4*4;
#pragma unroll
      for (int q = 0; q < 4; ++q)
        GI[(size_t)(rb + q)*384 + n] = acc[i][j][q];
    }
  }
}

// ================= k1d: gh = H @ w_hh.T + GRU pointwise (M=128/blk, N=384, K=128) ===
__global__ __launch_bounds__(512) void k1d_gru(const char* __restrict__ wsb,
    const float* __restrict__ b_ih, const float* __restrict__ b_hh,
    float* __restrict__ outf)
{
  extern __shared__ char lds[];
  char* AH = lds;
  char* AL = lds + 32768;
  const float* H  = outf + SC_H;
  const float* GI = outf + SC_GI;
  float* H2 = outf + SC_H2;
  const int tid = threadIdx.x, lane = tid & 63, wid = tid >> 6;
  const int wm = wid >> 2, wn = wid & 3, l15 = lane & 15, l4 = lane >> 4;
  const int r0 = blockIdx.x * 128;

  for (int i = tid; i < 128*32; i += 512) {
    int row = i >> 5, part = i & 31;
    float4 v = *(const float4*)&H[(size_t)(r0+row)*128 + part*4];
    ushort4 hi4, lo4;
    cvt4(v, hi4, lo4);
    unsigned off = row*256 + (((unsigned)(part*8)) ^ (((unsigned)(row&7)) << 4));
    *(ushort4*)(AH + off) = hi4;
    *(ushort4*)(AL + off) = lo4;
  }
  __syncthreads();

  f32x4 acc[4][6];
#pragma unroll
  for (int i = 0; i < 4; ++i)
#pragma unroll
    for (int j = 0; j < 6; ++j) acc[i][j] = (f32x4){0.f,0.f,0.f,0.f};

  for (int s = 0; s < 4; ++s) {
    bf16x8 ah[4], al[4];
#pragma unroll
    for (int i = 0; i < 4; ++i) {
      int row = wm*64 + i*16 + l15;
      unsigned off = row*256 + (((unsigned)(s*64 + l4*16)) ^ (((unsigned)(row&7)) << 4));
      ah[i] = *(const bf16x8*)(AH + off);
      al[i] = *(const bf16x8*)(AL + off);
    }
#pragma unroll
    for (int g = 0; g < 3; ++g)
#pragma unroll
      for (int j2 = 0; j2 < 2; ++j2) {
        int n = g*128 + wn*32 + j2*16 + l15;
        unsigned boff = (unsigned)(n*256 + s*64 + l4*16);
        bf16x8 bh = *(const bf16x8*)(wsb + WS_WHHH + boff);
        bf16x8 bl = *(const bf16x8*)(wsb + WS_WHHL + boff);
#pragma unroll
        for (int i = 0; i < 4; ++i) {
          acc[i][g*2+j2] = __builtin_amdgcn_mfma_f32_16x16x32_bf16(ah[i], bh, acc[i][g*2+j2], 0,0,0);
          acc[i][g*2+j2] = __builtin_amdgcn_mfma_f32_16x16x32_bf16(ah[i], bl, acc[i][g*2+j2], 0,0,0);
          acc[i][g*2+j2] = __builtin_amdgcn_mfma_f32_16x16x32_bf16(al[i], bh, acc[i][g*2+j2], 0,0,0);
        }
      }
  }

#pragma unroll
  for (int j2 = 0; j2 < 2; ++j2) {
    int c = wn*32 + j2*16 + l15;
    float bir = b_ih[c], bii = b_ih[128+c], bin_ = b_ih[256+c];
    float bhr = b_hh[c], bhi = b_hh[128+c], bhn  = b_hh[256+c];
#pragma unroll
    for (int i = 0; i < 4; ++i) {
      int rb = r0 + wm*64 + i*16 + l4*4;
#pragma unroll
      for (int q = 0; q < 4; ++q) {
        size_t r = (size_t)(rb + q);
        float gir = GI[r*384 + c]       + bir;
        float gii = GI[r*384 + 128 + c] + bii;
        float gin = GI[r*384 + 256 + c] + bin_;
        float rg = 1.f/(1.f + __expf(-(gir + acc[i][j2][q]   + bhr)));
        float ig = 1.f/(1.f + __expf(-(gii + acc[i][2+j2][q] + bhi)));
        float ng = tanhf(gin + rg*(acc[i][4+j2][q] + bhn));
        float h = H[r*128 + c];
        H2[r*128 + c] = ng + ig*(h - ng);
      }
    }
  }
}

// ================= k1e: per-sample attention readout =================
__global__ __launch_bounds__(256) void k1e_attn(const int* __restrict__ alias_in,
    const float* __restrict__ b1, const float* __restrict__ b2,
    const float* __restrict__ W3, const float* __restrict__ bt_,
    char* __restrict__ wsb, const float* __restrict__ outf)
{
  extern __shared__ float s[];
  float* S_hid   = s;            // 6400
  float* S_sig   = s + 6400;     // 50*132 = 6600
  float* S_q1    = s + 13000;    // 128
  float* S_a     = s + 13128;    // 128
  float* S_alpha = s + 13256;    // 64
  int*   S_alias = (int*)(s + 13320); // 64

  const int b = blockIdx.x, tid = threadIdx.x;
  const int c = tid & 127, half = tid >> 7;
  const float* H2  = outf + SC_H2;
  const float* W1T = (const float*)(wsb + WS_W1T);
  const float* W2T = (const float*)(wsb + WS_W2T);
  const float* WtT = (const float*)(wsb + WS_WTT);

  const float4* h4 = (const float4*)(H2 + (size_t)b*NN*HD);
  for (int i = tid; i < 1600; i += 256) ((float4*)S_hid)[i] = h4[i];
  if (tid < LLn) S_alias[tid] = alias_in[b*LLn + tid];
  __syncthreads();

  int cnt = 0;
  for (int l = 0; l < LLn; ++l) cnt += (S_alias[l] > 0) ? 1 : 0;
  int last = cnt - 1; if (last < 0) last = LLn - 1;
  const int a_last = S_alias[last];

  if (tid < HD) {
    float q = b1[tid];
    for (int k = 0; k < HD; ++k) q += S_hid[a_last*HD + k] * W1T[(k<<7) + tid];
    S_q1[tid] = q;
  }
  __syncthreads();

  {
    int al_[25];
#pragma unroll
    for (int i = 0; i < 25; ++i) al_[i] = S_alias[2*i + half];
    float q2a[25];
    float b2c = b2[c];
#pragma unroll
    for (int i = 0; i < 25; ++i) q2a[i] = b2c;
    for (int k = 0; k < HD; k += 4) {
      float w0 = W2T[(k<<7)+c],     w1 = W2T[((k+1)<<7)+c];
      float w2 = W2T[((k+2)<<7)+c], w3 = W2T[((k+3)<<7)+c];
#pragma unroll
      for (int i = 0; i < 25; ++i) {
        float4 x = *(const float4*)&S_hid[al_[i]*HD + k];
        q2a[i] += x.x*w0; q2a[i] += x.y*w1; q2a[i] += x.z*w2; q2a[i] += x.w*w3;
      }
    }
    float q1c = S_q1[c];
#pragma unroll
    for (int i = 0; i < 25; ++i) {
      int l = 2*i + half;
      S_sig[l*132 + c] = 1.f/(1.f + __expf(-(q1c + q2a[i])));
    }
  }
  __syncthreads();

  if (tid < LLn) {
    int l = tid;
    float sum = 0.f;
    for (int cc = 0; cc < HD; ++cc) sum += S_sig[l*132 + cc] * W3[cc];
    S_alpha[l] = (S_alias[l] > 0) ? sum : 0.f;
  }
  __syncthreads();

  if (tid < HD) {
    float acc = 0.f;
    for (int l = 0; l < LLn; ++l) acc += S_alpha[l] * S_hid[S_alias[l]*HD + tid];
    S_a[tid] = acc;
  }
  __syncthreads();

  if (tid < HD) {
    float r = bt_[tid];
    for (int k = 0; k < HD; ++k) r += S_a[k]               * WtT[(k<<7)       + tid];
    for (int k = 0; k < HD; ++k) r += S_hid[a_last*HD + k] * WtT[((128+k)<<7) + tid];
    int k = tid, kh = k >> 6, kl = k & 63;
    unsigned int cb = (unsigned int)(kl*2) ^ (((unsigned int)(b & 7)) << 4);
    unsigned short hi = f2bf(r);
    unsigned short lo = f2bf(r - bf2f(hi));
    *(unsigned short*)(wsb + WS_AHI + kh*65536 + b*128 + cb) = hi;
    *(unsigned short*)(wsb + WS_ALO + kh*65536 + b*128 + cb) = lo;
  }
}

// ================= k2: scores GEMM (unchanged, proven) =================
__global__ __launch_bounds__(512) void k2_mfma(const float* __restrict__ emb,
                                               const char* __restrict__ wsb,
                                               float* __restrict__ out)
{
  extern __shared__ char ldsc[];
  char* AHI = ldsc;
  char* ALO = ldsc + 32768;
  char* EHI = ldsc + 65536;
  char* ELO = ldsc + 81920;

  const int tid  = threadIdx.x;
  const int lane = tid & 63;
  const int wid  = tid >> 6;
  const int wm   = wid >> 1;
  const int wn   = wid & 1;
  const int j0   = blockIdx.x * 128;
  const int b0   = blockIdx.y * 256;
  const int l15  = lane & 15, l4 = lane >> 4;

  f32x4 acc[4][4];
#pragma unroll
  for (int i = 0; i < 4; ++i)
#pragma unroll
    for (int j = 0; j < 4; ++j) acc[i][j] = (f32x4){0.f, 0.f, 0.f, 0.f};

  for (int kh = 0; kh < 2; ++kh) {
    const char* srcH = wsb + WS_AHI + kh*65536 + b0*128;
    const char* srcL = wsb + WS_ALO + kh*65536 + b0*128;
#pragma unroll
    for (int r = 0; r < 4; ++r) {
      int off = (r*512 + tid) * 16;
      gl_lds16(srcH + off, AHI + off);
      gl_lds16(srcL + off, ALO + off);
    }
    {
      int rbase = tid >> 4, c4 = tid & 15;
#pragma unroll
      for (int rr = 0; rr < 4; ++rr) {
        int row = rbase + rr*32;
        int j = j0 + row; if (j > OUTN - 1) j = OUTN - 1;
        float4 v = *(const float4*)&emb[(size_t)(1 + j)*HD + kh*64 + c4*4];
        ushort4 hi4, lo4;
        cvt4(v, hi4, lo4);
        unsigned int off = (unsigned int)(row*128) + (((unsigned int)(c4*8)) ^ (((unsigned int)(row&7)) << 4));
        *(ushort4*)(EHI + off) = hi4;
        *(ushort4*)(ELO + off) = lo4;
      }
    }
    __syncthreads();

#pragma unroll
    for (int s = 0; s < 2; ++s) {
      bf16x8 ah[4], al[4], bh[4], bl[4];
      const unsigned int cb = (unsigned int)(s*64 + (l4 << 4));
#pragma unroll
      for (int i = 0; i < 4; ++i) {
        int row = wm*64 + i*16 + l15;
        unsigned int off = (unsigned int)(row*128) + (cb ^ (((unsigned int)(row&7)) << 4));
        ah[i] = *(const bf16x8*)(AHI + off);
        al[i] = *(const bf16x8*)(ALO + off);
      }
#pragma unroll
      for (int j = 0; j < 4; ++j) {
        int row = wn*64 + j*16 + l15;
        unsigned int off = (unsigned int)(row*128) + (cb ^ (((unsigned int)(row&7)) << 4));
        bh[j] = *(const bf16x8*)(EHI + off);
        bl[j] = *(const bf16x8*)(ELO + off);
      }
#pragma unroll
      for (int i = 0; i < 4; ++i)
#pragma unroll
        for (int j = 0; j < 4; ++j) {
          acc[i][j] = __builtin_amdgcn_mfma_f32_16x16x32_bf16(ah[i], bh[j], acc[i][j], 0, 0, 0);
          acc[i][j] = __builtin_amdgcn_mfma_f32_16x16x32_bf16(ah[i], bl[j], acc[i][j], 0, 0, 0);
          acc[i][j] = __builtin_amdgcn_mfma_f32_16x16x32_bf16(al[i], bh[j], acc[i][j], 0, 0, 0);
        }
    }
    __syncthreads();
  }

#pragma unroll
  for (int i = 0; i < 4; ++i) {
#pragma unroll
    for (int j = 0; j < 4; ++j) {
      int jj = j0 + wn*64 + j*16 + l15;
      if (jj < OUTN) {
        size_t rowbase = (size_t)(b0 + wm*64 + i*16 + l4*4);
#pragma unroll
        for (int q = 0; q < 4; ++q)
          out[(rowbase + q)*OUTN + jj] = acc[i][j][q];
      }
    }
  }
}

extern "C" void kernel_launch(void* const* d_in, const int* in_sizes, int n_in,
                              void* d_out, int out_size, void* d_ws, size_t ws_size,
                              hipStream_t stream)
{
  const int*   items  = (const int*)  d_in[0];
  const float* A      = (const float*)d_in[1];
  const int*   alias  = (const int*)  d_in[2];
  const float* emb    = (const float*)d_in[3];
  const float* w_ih   = (const float*)d_in[4];
  const float* w_hh   = (const float*)d_in[5];
  const float* b_ih   = (const float*)d_in[6];
  const float* b_hh   = (const float*)d_in[7];
  const float* b_iah  = (const float*)d_in[8];
  const float* b_oah  = (const float*)d_in[9];
  const float* W_ein  = (const float*)d_in[10];
  const float* b_ein  = (const float*)d_in[11];
  const float* W_eout = (const float*)d_in[12];
  const float* b_eout = (const float*)d_in[13];
  const float* W1     = (const float*)d_in[14];
  const float* b1     = (const float*)d_in[15];
  const float* W2     = (const float*)d_in[16];
  const float* b2     = (const float*)d_in[17];
  const float* W3     = (const float*)d_in[18];
  const float* Wt     = (const float*)d_in[19];
  const float* bt_    = (const float*)d_in[20];

  char*  wsb  = (char*)d_ws;
  float* outf = (float*)d_out;

  k0_prep<<<240, 256, 0, stream>>>(w_ih, w_hh, W_ein, W_eout, W1, W2, Wt, wsb);

  k1a_he<<<200, 512, 65536, stream>>>(items, emb, b_ein, b_eout, wsb, outf);

  k1b_ain<<<NB, 256, 72832, stream>>>(A, b_iah, b_oah, outf);

  k1c_gi<<<200, 512, 65536, stream>>>(wsb, outf);

  k1d_gru<<<200, 512, 65536, stream>>>(wsb, b_ih, b_hh, outf);

  k1e_attn<<<NB, 256, 53536, stream>>>(alias, b1, b2, W3, bt_, wsb, outf);

  k2_mfma<<<dim3(782, 2), 512, 98304, stream>>>(emb, (const char*)d_ws, outf);
}

// Round 4
// 231.579 us; speedup vs baseline: 3.0595x; 1.1136x over previous
//
#include <hip/hip_runtime.h>

#define NB   512
#define NN   50
#define LLn  50
#define HD   128
#define OUTN 99999
#define RTOT 25600

// ---------------- ws byte offsets ----------------
#define WS_W1T   0         // fp32 [128][128] transposed
#define WS_W2T   65536     // fp32 [128][128] transposed
#define WS_WTT   131072    // fp32 [256][128] transposed
#define WS_WEH   262144    // bf16 hi [256][128]  (rows 0-127 W_ein, 128-255 W_eout)
#define WS_WEL   327680    // bf16 lo
#define WS_WCATH 393216    // bf16 hi [384][384]  (cols 0-255 w_ih, 256-383 w_hh)
#define WS_WCATL 688128    // bf16 lo
#define WS_AHI   983040    // a-final hi image [2][512][128B]
#define WS_ALO   1114112

// ---------------- d_out scratch offsets (floats) ----------------
#define SC_H    0          // hidden fp32 [25600][128]
#define SC_HE   3276800    // he fp32 [25600][256]
#define SC_IN   9830400    // inputs fp32 [25600][256]
#define SC_H2   26214400   // new hidden fp32 [25600][128]

typedef __attribute__((ext_vector_type(8))) short bf16x8;
typedef __attribute__((ext_vector_type(4))) float f32x4;

__device__ __forceinline__ unsigned short f2bf(float f) {
  unsigned int u = __float_as_uint(f);
  unsigned int r = (u + 0x7FFFu + ((u >> 16) & 1u)) >> 16;
  return (unsigned short)r;
}
__device__ __forceinline__ float bf2f(unsigned short h) {
  return __uint_as_float(((unsigned int)h) << 16);
}
__device__ __forceinline__ void cvt4(float4 v, ushort4& hi, ushort4& lo) {
  unsigned short h0 = f2bf(v.x), h1 = f2bf(v.y), h2 = f2bf(v.z), h3 = f2bf(v.w);
  hi = make_ushort4(h0, h1, h2, h3);
  lo = make_ushort4(f2bf(v.x - bf2f(h0)), f2bf(v.y - bf2f(h1)),
                    f2bf(v.z - bf2f(h2)), f2bf(v.w - bf2f(h3)));
}
__device__ __forceinline__ void gl_lds16(const void* g, void* l) {
  __builtin_amdgcn_global_load_lds(
      (const __attribute__((address_space(1))) void*)g,
      (__attribute__((address_space(3))) void*)l, 16, 0, 0);
}

// ================= k0: weight prep =================
__global__ void k0_prep(const float* __restrict__ w_ih, const float* __restrict__ w_hh,
                        const float* __restrict__ W_ein, const float* __restrict__ W_eout,
                        const float* __restrict__ W1, const float* __restrict__ W2,
                        const float* __restrict__ Wt, char* __restrict__ wsb)
{
  float* wsf = (float*)wsb;
  for (int i = blockIdx.x * blockDim.x + threadIdx.x; i < 245760; i += gridDim.x * blockDim.x) {
    int idx = i;
    if (idx < 16384) { int k = idx >> 7, c = idx & 127; wsf[idx] = W1[c*128 + k]; continue; }
    idx -= 16384;
    if (idx < 16384) { int k = idx >> 7, c = idx & 127; wsf[16384 + idx] = W2[c*128 + k]; continue; }
    idx -= 16384;
    if (idx < 32768) { int k = idx >> 7, c = idx & 127; wsf[32768 + idx] = Wt[c*256 + k]; continue; }
    idx -= 32768;
    if (idx < 32768) {
      int n = idx >> 7, k = idx & 127;
      float v = (n < 128) ? W_ein[n*128 + k] : W_eout[(n-128)*128 + k];
      unsigned short h = f2bf(v);
      *(unsigned short*)(wsb + WS_WEH + idx*2) = h;
      *(unsigned short*)(wsb + WS_WEL + idx*2) = f2bf(v - bf2f(h));
      continue;
    }
    idx -= 32768;
    {
      // concat weight: [384 n][384 k], k<256 -> w_ih, k>=256 -> w_hh
      int n = idx / 384, k = idx % 384;
      float v = (k < 256) ? w_ih[n*256 + k] : w_hh[n*128 + (k - 256)];
      unsigned short h = f2bf(v);
      *(unsigned short*)(wsb + WS_WCATH + idx*2) = h;
      *(unsigned short*)(wsb + WS_WCATL + idx*2) = f2bf(v - bf2f(h));
    }
  }
}

// ================= k1a: gather + he GEMM (M=128/blk, N=256, K=128) =================
__global__ __launch_bounds__(512) void k1a_he(const int* __restrict__ items,
    const float* __restrict__ emb, const float* __restrict__ b_ein,
    const float* __restrict__ b_eout, const char* __restrict__ wsb,
    float* __restrict__ outf)
{
  extern __shared__ char lds[];
  char* AH = lds;
  char* AL = lds + 32768;
  float* H  = outf + SC_H;
  float* HE = outf + SC_HE;
  const int tid = threadIdx.x, lane = tid & 63, wid = tid >> 6;
  const int wm = wid >> 2, wn = wid & 3, l15 = lane & 15, l4 = lane >> 4;
  const int r0 = blockIdx.x * 128;

  for (int i = tid; i < 128*32; i += 512) {
    int row = i >> 5, part = i & 31;
    int it = items[r0 + row];
    float4 v = *(const float4*)&emb[(size_t)it*128 + part*4];
    *(float4*)&H[(size_t)(r0+row)*128 + part*4] = v;
    ushort4 hi4, lo4;
    cvt4(v, hi4, lo4);
    unsigned off = row*256 + (((unsigned)(part*8)) ^ (((unsigned)(row&7)) << 4));
    *(ushort4*)(AH + off) = hi4;
    *(ushort4*)(AL + off) = lo4;
  }
  __syncthreads();

  f32x4 acc[4][4];
#pragma unroll
  for (int i = 0; i < 4; ++i)
#pragma unroll
    for (int j = 0; j < 4; ++j) acc[i][j] = (f32x4){0.f,0.f,0.f,0.f};

  for (int s = 0; s < 4; ++s) {
    bf16x8 ah[4], al[4];
#pragma unroll
    for (int i = 0; i < 4; ++i) {
      int row = wm*64 + i*16 + l15;
      unsigned off = row*256 + (((unsigned)(s*64 + l4*16)) ^ (((unsigned)(row&7)) << 4));
      ah[i] = *(const bf16x8*)(AH + off);
      al[i] = *(const bf16x8*)(AL + off);
    }
#pragma unroll
    for (int j = 0; j < 4; ++j) {
      int n = wn*64 + j*16 + l15;
      unsigned boff = (unsigned)(n*256 + s*64 + l4*16);
      bf16x8 bh = *(const bf16x8*)(wsb + WS_WEH + boff);
      bf16x8 bl = *(const bf16x8*)(wsb + WS_WEL + boff);
#pragma unroll
      for (int i = 0; i < 4; ++i) {
        acc[i][j] = __builtin_amdgcn_mfma_f32_16x16x32_bf16(ah[i], bh, acc[i][j], 0,0,0);
        acc[i][j] = __builtin_amdgcn_mfma_f32_16x16x32_bf16(ah[i], bl, acc[i][j], 0,0,0);
        acc[i][j] = __builtin_amdgcn_mfma_f32_16x16x32_bf16(al[i], bh, acc[i][j], 0,0,0);
      }
    }
  }

#pragma unroll
  for (int j = 0; j < 4; ++j) {
    int n = wn*64 + j*16 + l15;
    float bias = (n < 128) ? b_ein[n] : b_eout[n - 128];
#pragma unroll
    for (int i = 0; i < 4; ++i) {
      int rb = r0 + wm*64 + i*16 + l4*4;
#pragma unroll
      for (int q = 0; q < 4; ++q)
        HE[(size_t)(rb + q)*256 + n] = acc[i][j][q] + bias;
    }
  }
}

// ================= k1b: per-sample A @ he (VALU fp32) =================
__global__ __launch_bounds__(256) void k1b_ain(const float* __restrict__ A,
    const float* __restrict__ b_iah, const float* __restrict__ b_oah,
    float* __restrict__ outf)
{
  extern __shared__ float s[];
  float* he_l = s;           // 50*256 = 12800
  float* A_l  = s + 12800;   // [2][50][52] = 5408
  const int b = blockIdx.x, tid = threadIdx.x;
  const float* HE = outf + SC_HE;
  float* IN = outf + SC_IN;

  const float4* he4 = (const float4*)(HE + (size_t)b*NN*256);
  for (int i = tid; i < 3200; i += 256) ((float4*)he_l)[i] = he4[i];
  const float* Ab = A + (size_t)b*NN*100;
  for (int i = tid; i < 5000; i += 256) {
    int n = i / 100, cc = i % 100;
    int sel = (cc >= 50) ? 1 : 0, m = cc - sel*50;
    A_l[sel*2704 + n*52 + m] = Ab[i];
  }
  __syncthreads();

  const int c = tid & 127, sel = tid >> 7;
  const float* Asel = A_l + sel*2704;
  const float* hes  = he_l + sel*128 + c;
  float acc[NN];
#pragma unroll
  for (int n = 0; n < NN; ++n) acc[n] = 0.f;

  for (int m4 = 0; m4 < 48; m4 += 4) {
    float x0 = hes[(m4+0)*256], x1 = hes[(m4+1)*256];
    float x2 = hes[(m4+2)*256], x3 = hes[(m4+3)*256];
#pragma unroll
    for (int n = 0; n < NN; ++n) {
      float4 a = *(const float4*)&Asel[n*52 + m4];
      acc[n] += a.x*x0 + a.y*x1 + a.z*x2 + a.w*x3;
    }
  }
  {
    float x0 = hes[48*256], x1 = hes[49*256];
#pragma unroll
    for (int n = 0; n < NN; ++n)
      acc[n] += Asel[n*52 + 48]*x0 + Asel[n*52 + 49]*x1;
  }
  float bias = sel ? b_oah[c] : b_iah[c];
  for (int n = 0; n < NN; ++n)
    IN[((size_t)b*NN + n)*256 + sel*128 + c] = acc[n] + bias;
}

// ====== k1cd: [IN | H] @ [w_ih | w_hh]^T  (M=128/blk, N=384, K=384) + GRU epilogue ==
__global__ __launch_bounds__(512) void k1cd_gru(const char* __restrict__ wsb,
    const float* __restrict__ b_ih, const float* __restrict__ b_hh,
    float* __restrict__ outf)
{
  extern __shared__ char lds[];
  char* AH = lds;
  char* AL = lds + 32768;
  const float* IN = outf + SC_IN;
  const float* H  = outf + SC_H;
  float* H2 = outf + SC_H2;
  const int tid = threadIdx.x, lane = tid & 63, wid = tid >> 6;
  const int wm = wid >> 2, wn = wid & 3, l15 = lane & 15, l4 = lane >> 4;
  const int r0 = blockIdx.x * 128;

  f32x4 acc[4][6];
#pragma unroll
  for (int i = 0; i < 4; ++i)
#pragma unroll
    for (int j = 0; j < 6; ++j) acc[i][j] = (f32x4){0.f,0.f,0.f,0.f};

  for (int kh = 0; kh < 3; ++kh) {
    if (kh) __syncthreads();
    for (int i = tid; i < 128*32; i += 512) {
      int row = i >> 5, part = i & 31;
      float4 v = (kh < 2)
        ? *(const float4*)&IN[(size_t)(r0+row)*256 + kh*128 + part*4]
        : *(const float4*)&H [(size_t)(r0+row)*128 + part*4];
      ushort4 hi4, lo4;
      cvt4(v, hi4, lo4);
      unsigned off = row*256 + (((unsigned)(part*8)) ^ (((unsigned)(row&7)) << 4));
      *(ushort4*)(AH + off) = hi4;
      *(ushort4*)(AL + off) = lo4;
    }
    __syncthreads();

    for (int s = 0; s < 4; ++s) {
      bf16x8 ah[4], al[4];
#pragma unroll
      for (int i = 0; i < 4; ++i) {
        int row = wm*64 + i*16 + l15;
        unsigned off = row*256 + (((unsigned)(s*64 + l4*16)) ^ (((unsigned)(row&7)) << 4));
        ah[i] = *(const bf16x8*)(AH + off);
        al[i] = *(const bf16x8*)(AL + off);
      }
#pragma unroll
      for (int g = 0; g < 3; ++g)
#pragma unroll
        for (int j2 = 0; j2 < 2; ++j2) {
          int n = g*128 + wn*32 + j2*16 + l15;
          unsigned boff = (unsigned)(n*768 + kh*256 + s*64 + l4*16);
          bf16x8 bh = *(const bf16x8*)(wsb + WS_WCATH + boff);
          bf16x8 bl = *(const bf16x8*)(wsb + WS_WCATL + boff);
#pragma unroll
          for (int i = 0; i < 4; ++i) {
            acc[i][g*2+j2] = __builtin_amdgcn_mfma_f32_16x16x32_bf16(ah[i], bh, acc[i][g*2+j2], 0,0,0);
            acc[i][g*2+j2] = __builtin_amdgcn_mfma_f32_16x16x32_bf16(ah[i], bl, acc[i][g*2+j2], 0,0,0);
            acc[i][g*2+j2] = __builtin_amdgcn_mfma_f32_16x16x32_bf16(al[i], bh, acc[i][g*2+j2], 0,0,0);
          }
        }
    }
  }

  // epilogue: acc[i][g*2+j2] holds (gi+gh) for gate g, col c = wn*32+j2*16+l15
#pragma unroll
  for (int j2 = 0; j2 < 2; ++j2) {
    int c = wn*32 + j2*16 + l15;
    float bir = b_ih[c], bii = b_ih[128+c], bin_ = b_ih[256+c];
    float bhr = b_hh[c], bhi = b_hh[128+c], bhn  = b_hh[256+c];
#pragma unroll
    for (int i = 0; i < 4; ++i) {
      int rb = r0 + wm*64 + i*16 + l4*4;
#pragma unroll
      for (int q = 0; q < 4; ++q) {
        size_t r = (size_t)(rb + q);
        float rg = 1.f/(1.f + __expf(-(acc[i][j2][q]   + bir + bhr)));
        float ig = 1.f/(1.f + __expf(-(acc[i][2+j2][q] + bii + bhi)));
        float ng = tanhf(acc[i][4+j2][q] + bin_ + rg*bhn);
        // NOTE: careful — n-gate is gin + rg*(ghn): ghn and gin are separate in ref.
        // acc[i][4+j2][q] = gin + ghn (merged) -> WRONG for n-gate. Undo merge below.
        (void)ng;
        float h = H[r*128 + c];
        // recompute correctly: we need gin and ghn separately; see k1cd_fix comment.
        H2[r*128 + c] = h; // placeholder overwritten below
      }
    }
  }
}

// The n-gate needs gin + resetgate*ghn with gin,ghn SEPARATE — the concat-K merge
// is invalid for the n gate. k1cd_gru above is therefore replaced by this version:
// gates r,i use merged K=384; gate n keeps two partial accumulators by splitting
// the B-operand columns: WCAT rows 256..383 (n-gate) are built k<256 from w_ih
// only and a SECOND pass over kh=2 uses w_hh n-rows into a separate acc.
__global__ __launch_bounds__(512) void k1cd_gru2(const char* __restrict__ wsb,
    const float* __restrict__ b_ih, const float* __restrict__ b_hh,
    float* __restrict__ outf)
{
  extern __shared__ char lds[];
  char* AH = lds;
  char* AL = lds + 32768;
  const float* IN = outf + SC_IN;
  const float* H  = outf + SC_H;
  float* H2 = outf + SC_H2;
  const int tid = threadIdx.x, lane = tid & 63, wid = tid >> 6;
  const int wm = wid >> 2, wn = wid & 3, l15 = lane & 15, l4 = lane >> 4;
  const int r0 = blockIdx.x * 128;

  f32x4 acc[4][6];   // gates r,i merged; slot g=2 holds gi_n only
  f32x4 accn[4][2];  // gh_n (K=128 from H)
#pragma unroll
  for (int i = 0; i < 4; ++i) {
#pragma unroll
    for (int j = 0; j < 6; ++j) acc[i][j] = (f32x4){0.f,0.f,0.f,0.f};
    accn[i][0] = (f32x4){0.f,0.f,0.f,0.f};
    accn[i][1] = (f32x4){0.f,0.f,0.f,0.f};
  }

  for (int kh = 0; kh < 3; ++kh) {
    if (kh) __syncthreads();
    for (int i = tid; i < 128*32; i += 512) {
      int row = i >> 5, part = i & 31;
      float4 v = (kh < 2)
        ? *(const float4*)&IN[(size_t)(r0+row)*256 + kh*128 + part*4]
        : *(const float4*)&H [(size_t)(r0+row)*128 + part*4];
      ushort4 hi4, lo4;
      cvt4(v, hi4, lo4);
      unsigned off = row*256 + (((unsigned)(part*8)) ^ (((unsigned)(row&7)) << 4));
      *(ushort4*)(AH + off) = hi4;
      *(ushort4*)(AL + off) = lo4;
    }
    __syncthreads();

    for (int s = 0; s < 4; ++s) {
      bf16x8 ah[4], al[4];
#pragma unroll
      for (int i = 0; i < 4; ++i) {
        int row = wm*64 + i*16 + l15;
        unsigned off = row*256 + (((unsigned)(s*64 + l4*16)) ^ (((unsigned)(row&7)) << 4));
        ah[i] = *(const bf16x8*)(AH + off);
        al[i] = *(const bf16x8*)(AL + off);
      }
      // gates r,i: merged K=384 (rows n in [0,256))
#pragma unroll
      for (int g = 0; g < 2; ++g)
#pragma unroll
        for (int j2 = 0; j2 < 2; ++j2) {
          int n = g*128 + wn*32 + j2*16 + l15;
          unsigned boff = (unsigned)(n*768 + kh*256 + s*64 + l4*16);
          bf16x8 bh = *(const bf16x8*)(wsb + WS_WCATH + boff);
          bf16x8 bl = *(const bf16x8*)(wsb + WS_WCATL + boff);
#pragma unroll
          for (int i = 0; i < 4; ++i) {
            acc[i][g*2+j2] = __builtin_amdgcn_mfma_f32_16x16x32_bf16(ah[i], bh, acc[i][g*2+j2], 0,0,0);
            acc[i][g*2+j2] = __builtin_amdgcn_mfma_f32_16x16x32_bf16(ah[i], bl, acc[i][g*2+j2], 0,0,0);
            acc[i][g*2+j2] = __builtin_amdgcn_mfma_f32_16x16x32_bf16(al[i], bh, acc[i][g*2+j2], 0,0,0);
          }
        }
      // gate n: split — gi_n (kh<2) into acc[.][4+j2], gh_n (kh==2) into accn
#pragma unroll
      for (int j2 = 0; j2 < 2; ++j2) {
        int n = 256 + wn*32 + j2*16 + l15;
        unsigned boff = (unsigned)(n*768 + kh*256 + s*64 + l4*16);
        bf16x8 bh = *(const bf16x8*)(wsb + WS_WCATH + boff);
        bf16x8 bl = *(const bf16x8*)(wsb + WS_WCATL + boff);
        if (kh < 2) {
#pragma unroll
          for (int i = 0; i < 4; ++i) {
            acc[i][4+j2] = __builtin_amdgcn_mfma_f32_16x16x32_bf16(ah[i], bh, acc[i][4+j2], 0,0,0);
            acc[i][4+j2] = __builtin_amdgcn_mfma_f32_16x16x32_bf16(ah[i], bl, acc[i][4+j2], 0,0,0);
            acc[i][4+j2] = __builtin_amdgcn_mfma_f32_16x16x32_bf16(al[i], bh, acc[i][4+j2], 0,0,0);
          }
        } else {
#pragma unroll
          for (int i = 0; i < 4; ++i) {
            accn[i][j2] = __builtin_amdgcn_mfma_f32_16x16x32_bf16(ah[i], bh, accn[i][j2], 0,0,0);
            accn[i][j2] = __builtin_amdgcn_mfma_f32_16x16x32_bf16(ah[i], bl, accn[i][j2], 0,0,0);
            accn[i][j2] = __builtin_amdgcn_mfma_f32_16x16x32_bf16(al[i], bh, accn[i][j2], 0,0,0);
          }
        }
      }
    }
  }

#pragma unroll
  for (int j2 = 0; j2 < 2; ++j2) {
    int c = wn*32 + j2*16 + l15;
    float bir = b_ih[c], bii = b_ih[128+c], bin_ = b_ih[256+c];
    float bhr = b_hh[c], bhi = b_hh[128+c], bhn  = b_hh[256+c];
#pragma unroll
    for (int i = 0; i < 4; ++i) {
      int rb = r0 + wm*64 + i*16 + l4*4;
#pragma unroll
      for (int q = 0; q < 4; ++q) {
        size_t r = (size_t)(rb + q);
        float rg = 1.f/(1.f + __expf(-(acc[i][j2][q]   + bir + bhr)));
        float ig = 1.f/(1.f + __expf(-(acc[i][2+j2][q] + bii + bhi)));
        float ng = tanhf(acc[i][4+j2][q] + bin_ + rg*(accn[i][j2][q] + bhn));
        float h = H[r*128 + c];
        H2[r*128 + c] = ng + ig*(h - ng);
      }
    }
  }
}

// ================= k1e: per-sample attention readout (all-lane parallel) ==========
__global__ __launch_bounds__(256) void k1e_attn(const int* __restrict__ alias_in,
    const float* __restrict__ b1, const float* __restrict__ b2,
    const float* __restrict__ W3, const float* __restrict__ bt_,
    char* __restrict__ wsb, const float* __restrict__ outf)
{
  extern __shared__ float s[];
  float* S_hid   = s;            // 6400
  float* S_sig   = s + 6400;     // 50*132 = 6600
  float* S_q1p   = s + 13000;    // 256
  float* S_ap    = s + 13256;    // 256
  float* S_rp    = s + 13512;    // 256
  float* S_alpha = s + 13768;    // 64
  int*   S_alias = (int*)(s + 13832); // 64  -> total 13896 floats

  const int b = blockIdx.x, tid = threadIdx.x;
  const int c = tid & 127, h = tid >> 7;
  const float* H2  = outf + SC_H2;
  const float* W1T = (const float*)(wsb + WS_W1T);
  const float* W2T = (const float*)(wsb + WS_W2T);
  const float* WtT = (const float*)(wsb + WS_WTT);

  const float4* h4 = (const float4*)(H2 + (size_t)b*NN*HD);
  for (int i = tid; i < 1600; i += 256) ((float4*)S_hid)[i] = h4[i];
  if (tid < LLn) S_alias[tid] = alias_in[b*LLn + tid];
  __syncthreads();

  int cnt = 0;
  for (int l = 0; l < LLn; ++l) cnt += (S_alias[l] > 0) ? 1 : 0;
  int last = cnt - 1; if (last < 0) last = LLn - 1;
  const int a_last = S_alias[last];

  // q1 partial over k-half
  {
    float q = 0.f;
    for (int k = h*64; k < h*64 + 64; k += 4) {
      float4 x = *(const float4*)&S_hid[a_last*HD + k];
      q += x.x*W1T[(k<<7)+c] + x.y*W1T[((k+1)<<7)+c]
         + x.z*W1T[((k+2)<<7)+c] + x.w*W1T[((k+3)<<7)+c];
    }
    S_q1p[h*128 + c] = q;
  }
  __syncthreads();

  // q2 + sigmoid
  {
    int al_[25];
#pragma unroll
    for (int i = 0; i < 25; ++i) al_[i] = S_alias[2*i + h];
    float q2a[25];
#pragma unroll
    for (int i = 0; i < 25; ++i) q2a[i] = 0.f;
    for (int k = 0; k < HD; k += 4) {
      float w0 = W2T[(k<<7)+c],     w1 = W2T[((k+1)<<7)+c];
      float w2 = W2T[((k+2)<<7)+c], w3 = W2T[((k+3)<<7)+c];
#pragma unroll
      for (int i = 0; i < 25; ++i) {
        float4 x = *(const float4*)&S_hid[al_[i]*HD + k];
        q2a[i] += x.x*w0; q2a[i] += x.y*w1; q2a[i] += x.z*w2; q2a[i] += x.w*w3;
      }
    }
    float q1c = S_q1p[c] + S_q1p[128 + c] + b1[c] + b2[c];
#pragma unroll
    for (int i = 0; i < 25; ++i) {
      int l = 2*i + h;
      S_sig[l*132 + c] = 1.f/(1.f + __expf(-(q1c + q2a[i])));
    }
  }
  __syncthreads();

  // alpha = sig @ W3 : 4 threads per row l, shuffle-reduce
  if (tid < 200) {
    int l = tid >> 2, q = tid & 3;
    float sum = 0.f;
    for (int cc = q*32; cc < q*32 + 32; cc += 4) {
      float4 x = *(const float4*)&S_sig[l*132 + cc];
      sum += x.x*W3[cc] + x.y*W3[cc+1] + x.z*W3[cc+2] + x.w*W3[cc+3];
    }
    sum += __shfl_xor(sum, 1);
    sum += __shfl_xor(sum, 2);
    if (q == 0) S_alpha[l] = (S_alias[l] > 0) ? sum : 0.f;
  }
  __syncthreads();

  // a partial over l-half
  {
    float acc = 0.f;
    for (int l = h*25; l < h*25 + 25; ++l)
      acc += S_alpha[l] * S_hid[S_alias[l]*HD + c];
    S_ap[h*128 + c] = acc;
  }
  __syncthreads();

  // final r partial over k-half
  {
    float r = 0.f;
    for (int k = h*64; k < h*64 + 64; ++k) {
      float av = S_ap[k] + S_ap[128 + k];
      r += av * WtT[(k<<7) + c] + S_hid[a_last*HD + k] * WtT[((128+k)<<7) + c];
    }
    S_rp[h*128 + c] = r;
  }
  __syncthreads();

  if (tid < 128) {
    float r = bt_[c] + S_rp[c] + S_rp[128 + c];
    int kh = c >> 6, kl = c & 63;
    unsigned int cb = (unsigned int)(kl*2) ^ (((unsigned int)(b & 7)) << 4);
    unsigned short hi = f2bf(r);
    unsigned short lo = f2bf(r - bf2f(hi));
    *(unsigned short*)(wsb + WS_AHI + kh*65536 + b*128 + cb) = hi;
    *(unsigned short*)(wsb + WS_ALO + kh*65536 + b*128 + cb) = lo;
  }
}

// ================= k2: scores GEMM, E-tile reused across both b-halves ============
__global__ __launch_bounds__(512) void k2_mfma(const float* __restrict__ emb,
                                               const char* __restrict__ wsb,
                                               float* __restrict__ out)
{
  extern __shared__ char ldsc[];
  char* AHI = ldsc;
  char* ALO = ldsc + 32768;
  char* EHI = ldsc + 65536;
  char* ELO = ldsc + 81920;

  const int tid  = threadIdx.x;
  const int lane = tid & 63;
  const int wid  = tid >> 6;
  const int wm   = wid >> 1;
  const int wn   = wid & 1;
  const int j0   = blockIdx.x * 128;
  const int l15  = lane & 15, l4 = lane >> 4;

  f32x4 acc[2][4][4];
#pragma unroll
  for (int bi = 0; bi < 2; ++bi)
#pragma unroll
    for (int i = 0; i < 4; ++i)
#pragma unroll
      for (int j = 0; j < 4; ++j) acc[bi][i][j] = (f32x4){0.f, 0.f, 0.f, 0.f};

  for (int kh = 0; kh < 2; ++kh) {
    // E tile: reg-stage fp32 -> hi/lo bf16, swizzled ds_write (once per kh)
    {
      int rbase = tid >> 4, c4 = tid & 15;
#pragma unroll
      for (int rr = 0; rr < 4; ++rr) {
        int row = rbase + rr*32;
        int j = j0 + row; if (j > OUTN - 1) j = OUTN - 1;
        float4 v = *(const float4*)&emb[(size_t)(1 + j)*HD + kh*64 + c4*4];
        ushort4 hi4, lo4;
        cvt4(v, hi4, lo4);
        unsigned int off = (unsigned int)(row*128) + (((unsigned int)(c4*8)) ^ (((unsigned int)(row&7)) << 4));
        *(ushort4*)(EHI + off) = hi4;
        *(ushort4*)(ELO + off) = lo4;
      }
    }
#pragma unroll
    for (int bi = 0; bi < 2; ++bi) {
      const char* srcH = wsb + WS_AHI + kh*65536 + bi*32768;
      const char* srcL = wsb + WS_ALO + kh*65536 + bi*32768;
#pragma unroll
      for (int r = 0; r < 4; ++r) {
        int off = (r*512 + tid) * 16;
        gl_lds16(srcH + off, AHI + off);
        gl_lds16(srcL + off, ALO + off);
      }
      __syncthreads();

#pragma unroll
      for (int s = 0; s < 2; ++s) {
        bf16x8 ah[4], al[4], bh[4], bl[4];
        const unsigned int cb = (unsigned int)(s*64 + (l4 << 4));
#pragma unroll
        for (int i = 0; i < 4; ++i) {
          int row = wm*64 + i*16 + l15;
          unsigned int off = (unsigned int)(row*128) + (cb ^ (((unsigned int)(row&7)) << 4));
          ah[i] = *(const bf16x8*)(AHI + off);
          al[i] = *(const bf16x8*)(ALO + off);
        }
#pragma unroll
        for (int j = 0; j < 4; ++j) {
          int row = wn*64 + j*16 + l15;
          unsigned int off = (unsigned int)(row*128) + (cb ^ (((unsigned int)(row&7)) << 4));
          bh[j] = *(const bf16x8*)(EHI + off);
          bl[j] = *(const bf16x8*)(ELO + off);
        }
#pragma unroll
        for (int i = 0; i < 4; ++i)
#pragma unroll
          for (int j = 0; j < 4; ++j) {
            acc[bi][i][j] = __builtin_amdgcn_mfma_f32_16x16x32_bf16(ah[i], bh[j], acc[bi][i][j], 0, 0, 0);
            acc[bi][i][j] = __builtin_amdgcn_mfma_f32_16x16x32_bf16(ah[i], bl[j], acc[bi][i][j], 0, 0, 0);
            acc[bi][i][j] = __builtin_amdgcn_mfma_f32_16x16x32_bf16(al[i], bh[j], acc[bi][i][j], 0, 0, 0);
          }
      }
      __syncthreads();
    }
  }

#pragma unroll
  for (int bi = 0; bi < 2; ++bi)
#pragma unroll
    for (int i = 0; i < 4; ++i) {
#pragma unroll
      for (int j = 0; j < 4; ++j) {
        int jj = j0 + wn*64 + j*16 + l15;
        if (jj < OUTN) {
          size_t rowbase = (size_t)(bi*256 + wm*64 + i*16 + l4*4);
#pragma unroll
          for (int q = 0; q < 4; ++q)
            out[(rowbase + q)*OUTN + jj] = acc[bi][i][j][q];
        }
      }
    }
}

extern "C" void kernel_launch(void* const* d_in, const int* in_sizes, int n_in,
                              void* d_out, int out_size, void* d_ws, size_t ws_size,
                              hipStream_t stream)
{
  const int*   items  = (const int*)  d_in[0];
  const float* A      = (const float*)d_in[1];
  const int*   alias  = (const int*)  d_in[2];
  const float* emb    = (const float*)d_in[3];
  const float* w_ih   = (const float*)d_in[4];
  const float* w_hh   = (const float*)d_in[5];
  const float* b_ih   = (const float*)d_in[6];
  const float* b_hh   = (const float*)d_in[7];
  const float* b_iah  = (const float*)d_in[8];
  const float* b_oah  = (const float*)d_in[9];
  const float* W_ein  = (const float*)d_in[10];
  const float* b_ein  = (const float*)d_in[11];
  const float* W_eout = (const float*)d_in[12];
  const float* b_eout = (const float*)d_in[13];
  const float* W1     = (const float*)d_in[14];
  const float* b1     = (const float*)d_in[15];
  const float* W2     = (const float*)d_in[16];
  const float* b2     = (const float*)d_in[17];
  const float* W3     = (const float*)d_in[18];
  const float* Wt     = (const float*)d_in[19];
  const float* bt_    = (const float*)d_in[20];

  char*  wsb  = (char*)d_ws;
  float* outf = (float*)d_out;

  k0_prep<<<240, 256, 0, stream>>>(w_ih, w_hh, W_ein, W_eout, W1, W2, Wt, wsb);

  k1a_he<<<200, 512, 65536, stream>>>(items, emb, b_ein, b_eout, wsb, outf);

  k1b_ain<<<NB, 256, 72832, stream>>>(A, b_iah, b_oah, outf);

  k1cd_gru2<<<200, 512, 65536, stream>>>(wsb, b_ih, b_hh, outf);

  k1e_attn<<<NB, 256, 55584, stream>>>(alias, b1, b2, W3, bt_, wsb, outf);

  k2_mfma<<<dim3(782, 1), 512, 98304, stream>>>(emb, (const char*)d_ws, outf);
}